// Round 1
// baseline (232.820 us; speedup 1.0000x reference)
//
#include <hip/hip_runtime.h>
#include <hip/hip_bf16.h>

typedef __attribute__((ext_vector_type(8))) short short8;
typedef __attribute__((ext_vector_type(4))) float floatx4;

#define MFMA_BF16(a, b, c) __builtin_amdgcn_mfma_f32_16x16x32_bf16((a), (b), (c), 0, 0, 0)

__device__ __forceinline__ unsigned short f2bf(float f) {
    union { float f; unsigned u; } v; v.f = f;
    unsigned r = v.u + 0x7fffu + ((v.u >> 16) & 1u);
    return (unsigned short)(r >> 16);
}

// ---------------- elementwise cast f32 -> bf16 ----------------
__global__ void cast_f32_to_bf16(const float* __restrict__ src,
                                 unsigned short* __restrict__ dst, int n4) {
    int i = blockIdx.x * blockDim.x + threadIdx.x;
    int stride = gridDim.x * blockDim.x;
    for (; i < n4; i += stride) {
        float4 f = reinterpret_cast<const float4*>(src)[i];
        ushort4 o;
        o.x = f2bf(f.x); o.y = f2bf(f.y); o.z = f2bf(f.z); o.w = f2bf(f.w);
        reinterpret_cast<ushort4*>(dst)[i] = o;
    }
}

// ---------- transpose + cast: src[R][C] f32 -> dst[C][R] bf16 (R,C multiples of 32) ----------
__global__ void transpose_cast(const float* __restrict__ src,
                               unsigned short* __restrict__ dst, int R, int C) {
    __shared__ float tile[32][33];
    int c0 = blockIdx.x * 32, r0 = blockIdx.y * 32;
    int tx = threadIdx.x, ty = threadIdx.y;
#pragma unroll
    for (int i = 0; i < 32; i += 8)
        tile[ty + i][tx] = src[(long)(r0 + ty + i) * C + (c0 + tx)];
    __syncthreads();
#pragma unroll
    for (int i = 0; i < 32; i += 8)
        dst[(long)(c0 + ty + i) * R + (r0 + tx)] = f2bf(tile[tx][ty + i]);
}

// ---------------- 128x128 bf16 MFMA GEMM, B given as B^T ([N][K] row-major) ----------------
// C[m][n] = sum_k A[m][k] * B[n][k].  OUT_BF16: store bf16; else fp32 + bias.
template <bool OUT_BF16>
__global__ __launch_bounds__(256, 2) void gemm_bt(
    const unsigned short* __restrict__ A,   // [M][K] bf16
    const unsigned short* __restrict__ B,   // [N][K] bf16
    void* __restrict__ Cout,
    const float* __restrict__ bias,
    int M, int N, int K) {
    const int LDT = 40;  // padded LDS row (shorts): 80B, 16B-aligned, 2-way-free banks
    __shared__ __align__(16) unsigned short Alds[128 * LDT];
    __shared__ __align__(16) unsigned short Blds[128 * LDT];

    int tid = threadIdx.x;
    int lane = tid & 63, wave = tid >> 6;
    int m0 = blockIdx.y * 128, n0 = blockIdx.x * 128;
    int wm = (wave >> 1) * 64, wn = (wave & 1) * 64;

    floatx4 acc[4][4];
#pragma unroll
    for (int mi = 0; mi < 4; mi++)
#pragma unroll
        for (int ni = 0; ni < 4; ni++) acc[mi][ni] = (floatx4){0.f, 0.f, 0.f, 0.f};

    int srow = tid >> 1;   // 0..127
    int shalf = tid & 1;   // k halves of 16
    int arow = m0 + srow; if (arow >= M) arow = M - 1;
    const unsigned short* aptr = A + (long)arow * K + shalf * 16;
    const unsigned short* bptr = B + (long)(n0 + srow) * K + shalf * 16;
    unsigned short* aw = &Alds[srow * LDT + shalf * 16];
    unsigned short* bw = &Blds[srow * LDT + shalf * 16];

    for (int k0 = 0; k0 < K; k0 += 32) {
        short8 av0 = *reinterpret_cast<const short8*>(aptr + k0);
        short8 av1 = *reinterpret_cast<const short8*>(aptr + k0 + 8);
        short8 bv0 = *reinterpret_cast<const short8*>(bptr + k0);
        short8 bv1 = *reinterpret_cast<const short8*>(bptr + k0 + 8);
        __syncthreads();
        *reinterpret_cast<short8*>(aw) = av0;
        *reinterpret_cast<short8*>(aw + 8) = av1;
        *reinterpret_cast<short8*>(bw) = bv0;
        *reinterpret_cast<short8*>(bw + 8) = bv1;
        __syncthreads();

        short8 af[4], bfr[4];
#pragma unroll
        for (int mi = 0; mi < 4; mi++)
            af[mi] = *reinterpret_cast<const short8*>(
                &Alds[(wm + mi * 16 + (lane & 15)) * LDT + (lane >> 4) * 8]);
#pragma unroll
        for (int ni = 0; ni < 4; ni++)
            bfr[ni] = *reinterpret_cast<const short8*>(
                &Blds[(wn + ni * 16 + (lane & 15)) * LDT + (lane >> 4) * 8]);
#pragma unroll
        for (int mi = 0; mi < 4; mi++)
#pragma unroll
            for (int ni = 0; ni < 4; ni++)
                acc[mi][ni] = MFMA_BF16(af[mi], bfr[ni], acc[mi][ni]);
    }

    // epilogue: D layout row=(lane>>4)*4+r, col=lane&15
    if (OUT_BF16) {
        unsigned short* C = (unsigned short*)Cout;
#pragma unroll
        for (int mi = 0; mi < 4; mi++)
#pragma unroll
            for (int rr = 0; rr < 4; rr++) {
                int row = m0 + wm + mi * 16 + (lane >> 4) * 4 + rr;
                if (row < M) {
                    long rbase = (long)row * N + n0 + wn + (lane & 15);
#pragma unroll
                    for (int ni = 0; ni < 4; ni++)
                        C[rbase + ni * 16] = f2bf(acc[mi][ni][rr]);
                }
            }
    } else {
        float* C = (float*)Cout;
        float bv[4];
#pragma unroll
        for (int ni = 0; ni < 4; ni++) bv[ni] = bias[n0 + wn + ni * 16 + (lane & 15)];
#pragma unroll
        for (int mi = 0; mi < 4; mi++)
#pragma unroll
            for (int rr = 0; rr < 4; rr++) {
                int row = m0 + wm + mi * 16 + (lane >> 4) * 4 + rr;
                if (row < M) {
                    long rbase = (long)row * N + n0 + wn + (lane & 15);
#pragma unroll
                    for (int ni = 0; ni < 4; ni++)
                        C[rbase + ni * 16] = acc[mi][ni][rr] + bv[ni];
                }
            }
    }
}

// ---------------- fused attention: one block per (b,h) ----------------
// qkv: [B*197][2304] bf16 rows (q|k|v each [12 heads][64]); out: [B*197][768] bf16
__global__ __launch_bounds__(448, 2) void attn_kernel(
    const unsigned short* __restrict__ qkv,
    const float* __restrict__ scale,
    unsigned short* __restrict__ out) {
    const int N = 197, D3 = 2304;
    int b = blockIdx.x / 12, h = blockIdx.x % 12;
    int tid = threadIdx.x, lane = tid & 63, wave = tid >> 6;

    __shared__ __align__(16) unsigned short Klds[224 * 64];   // [key row][d], 16B slots XOR (r&7)
    __shared__ __align__(16) unsigned short Vlds[64 * 224];   // [d][j], 16B slots XOR (d&3)
    __shared__ __align__(16) unsigned short Plds[7 * 16 * 32];// per-wave P chunk, slots XOR (row&3)

    const unsigned short* base = qkv + (long)b * N * D3 + h * 64;

    // stage K (zero-pad rows >= N), swizzled
    for (int idx = tid; idx < 224 * 8; idx += 448) {
        int r = idx >> 3, s = idx & 7;
        short8 v = {0, 0, 0, 0, 0, 0, 0, 0};
        if (r < N) v = *reinterpret_cast<const short8*>(base + (long)r * D3 + 768 + s * 8);
        *reinterpret_cast<short8*>(&Klds[r * 64 + (s ^ (r & 7)) * 8]) = v;
    }
    // stage V transposed (Vlds[d][j]), zero-pad
    for (int idx = tid; idx < 224 * 8; idx += 448) {
        int j = idx >> 3, sg = idx & 7;
        short8 v = {0, 0, 0, 0, 0, 0, 0, 0};
        if (j < N) v = *reinterpret_cast<const short8*>(base + (long)j * D3 + 1536 + sg * 8);
        int s = j >> 3;
#pragma unroll
        for (int e = 0; e < 8; e++) {
            int d = sg * 8 + e;
            Vlds[d * 224 + (s ^ (d & 3)) * 8 + (j & 7)] = (unsigned short)v[e];
        }
    }
    __syncthreads();

    float sc = scale[h];
    unsigned short* Pw = &Plds[wave * (16 * 32)];

    for (int rtb = 0; rtb < 2; rtb++) {
        int rt = wave + rtb * 7;  // 0..13
        int i0 = rt * 16;
        // Q fragments (A operand: row = lane&15, k = (lane>>4)*8+e), clamped global rows
        int qrow = i0 + (lane & 15); if (qrow > N - 1) qrow = N - 1;
        const unsigned short* qp = base + (long)qrow * D3;
        short8 qf[2];
#pragma unroll
        for (int kb = 0; kb < 2; kb++)
            qf[kb] = *reinterpret_cast<const short8*>(qp + kb * 32 + (lane >> 4) * 8);

        // S = Q @ K^T  (B operand row j = lane&15 reads K row contiguously)
        floatx4 sf[14];
#pragma unroll
        for (int jt = 0; jt < 14; jt++) sf[jt] = (floatx4){0.f, 0.f, 0.f, 0.f};
#pragma unroll
        for (int jt = 0; jt < 14; jt++) {
#pragma unroll
            for (int kb = 0; kb < 2; kb++) {
                int r = jt * 16 + (lane & 15);
                int slot = kb * 4 + (lane >> 4);
                short8 kf = *reinterpret_cast<const short8*>(
                    &Klds[r * 64 + (slot ^ (r & 7)) * 8]);
                sf[jt] = MFMA_BF16(qf[kb], kf, sf[jt]);
            }
        }

        // softmax over j (rows: (lane>>4)*4+rr; cols: jt*16 + (lane&15))
        int rowg[4];
        float mx[4], sm[4];
#pragma unroll
        for (int rr = 0; rr < 4; rr++) { rowg[rr] = i0 + (lane >> 4) * 4 + rr; mx[rr] = -1e30f; }
#pragma unroll
        for (int jt = 0; jt < 14; jt++) {
            int col = jt * 16 + (lane & 15);
#pragma unroll
            for (int rr = 0; rr < 4; rr++) {
                float v = sf[jt][rr] * sc;
                if (col >= N || col == rowg[rr]) v = -1e30f;  // tail + diagonal mask
                sf[jt][rr] = v;
                mx[rr] = fmaxf(mx[rr], v);
            }
        }
#pragma unroll
        for (int rr = 0; rr < 4; rr++) {
#pragma unroll
            for (int m = 1; m <= 8; m <<= 1)
                mx[rr] = fmaxf(mx[rr], __shfl_xor(mx[rr], m, 64));
            sm[rr] = 0.f;
        }
#pragma unroll
        for (int jt = 0; jt < 14; jt++)
#pragma unroll
            for (int rr = 0; rr < 4; rr++) {
                float p = __expf(sf[jt][rr] - mx[rr]);
                sf[jt][rr] = p;
                sm[rr] += p;
            }
#pragma unroll
        for (int rr = 0; rr < 4; rr++)
#pragma unroll
            for (int m = 1; m <= 8; m <<= 1)
                sm[rr] += __shfl_xor(sm[rr], m, 64);

        // PV: per 32-col chunk, transpose P via per-wave LDS, then 4 MFMAs vs V^T
        floatx4 oacc[4];
#pragma unroll
        for (int dt = 0; dt < 4; dt++) oacc[dt] = (floatx4){0.f, 0.f, 0.f, 0.f};
#pragma unroll
        for (int c = 0; c < 7; c++) {
#pragma unroll
            for (int jh = 0; jh < 2; jh++) {
#pragma unroll
                for (int rr = 0; rr < 4; rr++) {
                    int row = (lane >> 4) * 4 + rr;
                    int jj = jh * 16 + (lane & 15);
                    Pw[row * 32 + ((jj >> 3) ^ (row & 3)) * 8 + (jj & 7)] =
                        f2bf(sf[c * 2 + jh][rr]);
                }
            }
            int prow = lane & 15;
            short8 pa = *reinterpret_cast<const short8*>(
                &Pw[prow * 32 + (((lane >> 4)) ^ (prow & 3)) * 8]);
#pragma unroll
            for (int dt = 0; dt < 4; dt++) {
                int d = dt * 16 + (lane & 15);
                int slot = c * 4 + (lane >> 4);
                short8 vf = *reinterpret_cast<const short8*>(
                    &Vlds[d * 224 + (slot ^ (d & 3)) * 8]);
                oacc[dt] = MFMA_BF16(pa, vf, oacc[dt]);
            }
        }

        // write out (divide by softmax denom here)
#pragma unroll
        for (int rr = 0; rr < 4; rr++) {
            int n = rowg[rr];
            if (n < N) {
                float r = 1.f / sm[rr];
                long o = ((long)b * N + n) * 768 + h * 64;
#pragma unroll
                for (int dt = 0; dt < 4; dt++)
                    out[o + dt * 16 + (lane & 15)] = f2bf(oacc[dt][rr] * r);
            }
        }
    }
}

extern "C" void kernel_launch(void* const* d_in, const int* in_sizes, int n_in,
                              void* d_out, int out_size, void* d_ws, size_t ws_size,
                              hipStream_t stream) {
    (void)in_sizes; (void)n_in; (void)out_size; (void)ws_size;
    const float* x     = (const float*)d_in[0];
    const float* scale = (const float*)d_in[1];
    const float* Wqkv  = (const float*)d_in[2];
    const float* Wout  = (const float*)d_in[3];
    const float* bout  = (const float*)d_in[4];
    float* out = (float*)d_out;

    const int M = 12608;  // 64*197
    char* ws = (char*)d_ws;
    unsigned short* x_bf   = (unsigned short*)(ws);                     // 19365888 B
    unsigned short* wqkv_t = (unsigned short*)(ws + 19365888);          //  3538944 B
    unsigned short* wout_t = (unsigned short*)(ws + 22904832);          //  1179648 B
    unsigned short* qkv    = (unsigned short*)(ws + 24084480);          // 58097664 B
    unsigned short* ao     = (unsigned short*)(ws + 82182144);          // 19365888 B

    cast_f32_to_bf16<<<2048, 256, 0, stream>>>(x, x_bf, (M * 768) / 4);
    transpose_cast<<<dim3(2304 / 32, 768 / 32), dim3(32, 8), 0, stream>>>(Wqkv, wqkv_t, 768, 2304);
    transpose_cast<<<dim3(768 / 32, 768 / 32), dim3(32, 8), 0, stream>>>(Wout, wout_t, 768, 768);
    gemm_bt<true><<<dim3(2304 / 128, 99), 256, 0, stream>>>(x_bf, wqkv_t, qkv, nullptr, M, 2304, 768);
    attn_kernel<<<768, 448, 0, stream>>>(qkv, scale, ao);
    gemm_bt<false><<<dim3(768 / 128, 99), 256, 0, stream>>>(ao, wout_t, out, bout, M, 768, 768);
}

// Round 2
// 219.749 us; speedup vs baseline: 1.0595x; 1.0595x over previous
//
#include <hip/hip_runtime.h>
#include <hip/hip_bf16.h>

typedef __attribute__((ext_vector_type(8))) short short8;
typedef __attribute__((ext_vector_type(4))) float floatx4;

#define MFMA_BF16(a, b, c) __builtin_amdgcn_mfma_f32_16x16x32_bf16((a), (b), (c), 0, 0, 0)

__device__ __forceinline__ unsigned short f2bf(float f) {
    union { float f; unsigned u; } v; v.f = f;
    unsigned r = v.u + 0x7fffu + ((v.u >> 16) & 1u);
    return (unsigned short)(r >> 16);
}

// async global->LDS, 16B per lane (global_load_lds_dwordx4)
__device__ __forceinline__ void gload16(const unsigned short* g, unsigned short* l) {
    __builtin_amdgcn_global_load_lds(
        (const __attribute__((address_space(1))) unsigned int*)g,
        (__attribute__((address_space(3))) unsigned int*)l, 16, 0, 0);
}

// ---------------- elementwise cast f32 -> bf16 ----------------
__global__ void cast_f32_to_bf16(const float* __restrict__ src,
                                 unsigned short* __restrict__ dst, int n4) {
    int i = blockIdx.x * blockDim.x + threadIdx.x;
    int stride = gridDim.x * blockDim.x;
    for (; i < n4; i += stride) {
        float4 f = reinterpret_cast<const float4*>(src)[i];
        ushort4 o;
        o.x = f2bf(f.x); o.y = f2bf(f.y); o.z = f2bf(f.z); o.w = f2bf(f.w);
        reinterpret_cast<ushort4*>(dst)[i] = o;
    }
}

// ---------- transpose + cast: src[R][C] f32 -> dst[C][R] bf16 (R,C multiples of 32) ----------
__global__ void transpose_cast(const float* __restrict__ src,
                               unsigned short* __restrict__ dst, int R, int C) {
    __shared__ float tile[32][33];
    int c0 = blockIdx.x * 32, r0 = blockIdx.y * 32;
    int tx = threadIdx.x, ty = threadIdx.y;
#pragma unroll
    for (int i = 0; i < 32; i += 8)
        tile[ty + i][tx] = src[(long)(r0 + ty + i) * C + (c0 + tx)];
    __syncthreads();
#pragma unroll
    for (int i = 0; i < 32; i += 8)
        dst[(long)(c0 + ty + i) * R + (r0 + tx)] = f2bf(tile[tx][ty + i]);
}

// ---------------- 128x128 bf16 MFMA GEMM (m97 structure), B given as B^T ----------------
// C[m][n] = sum_k A[m][k] * B[n][k].  Linear LDS [128][32] shorts, global_load_lds x16.
template <bool OUT_BF16>
__global__ __launch_bounds__(256, 4) void gemm_bt(
    const unsigned short* __restrict__ A,   // [M][K] bf16
    const unsigned short* __restrict__ B,   // [N][K] bf16
    void* __restrict__ Cout,
    const float* __restrict__ bias,
    int M, int N, int K) {
    __shared__ __align__(16) unsigned short Alds[128 * 32];
    __shared__ __align__(16) unsigned short Blds[128 * 32];

    int tid = threadIdx.x;
    int lane = tid & 63, wave = tid >> 6;
    int m0 = blockIdx.y * 128, n0 = blockIdx.x * 128;
    int wm = (wave >> 1) * 64, wn = (wave & 1) * 64;

    floatx4 acc[4][4];
#pragma unroll
    for (int mi = 0; mi < 4; mi++)
#pragma unroll
        for (int ni = 0; ni < 4; ni++) acc[mi][ni] = (floatx4){0.f, 0.f, 0.f, 0.f};

    // staging map: thread covers LDS bytes tid*16 (rows 0..63) and 4096+tid*16 (rows 64..127)
    int srow = tid >> 2;        // 0..63
    int scol = (tid & 3) * 8;   // short offset within row (K-direction)
    int ar0 = m0 + srow;       if (ar0 >= M) ar0 = M - 1;
    int ar1 = m0 + 64 + srow;  if (ar1 >= M) ar1 = M - 1;
    const unsigned short* ap0 = A + (long)ar0 * K + scol;
    const unsigned short* ap1 = A + (long)ar1 * K + scol;
    const unsigned short* bp0 = B + (long)(n0 + srow) * K + scol;
    const unsigned short* bp1 = B + (long)(n0 + 64 + srow) * K + scol;
    unsigned short* la0 = &Alds[srow * 32 + scol];
    unsigned short* la1 = &Alds[(64 + srow) * 32 + scol];
    unsigned short* lb0 = &Blds[srow * 32 + scol];
    unsigned short* lb1 = &Blds[(64 + srow) * 32 + scol];

    for (int k0 = 0; k0 < K; k0 += 32) {
        __syncthreads();              // previous iter's reads done before overwrite
        gload16(ap0 + k0, la0);
        gload16(ap1 + k0, la1);
        gload16(bp0 + k0, lb0);
        gload16(bp1 + k0, lb1);
        __syncthreads();              // drains vmcnt(0) + joins

        short8 af[4], bfr[4];
#pragma unroll
        for (int mi = 0; mi < 4; mi++)
            af[mi] = *reinterpret_cast<const short8*>(
                &Alds[(wm + mi * 16 + (lane & 15)) * 32 + (lane >> 4) * 8]);
#pragma unroll
        for (int ni = 0; ni < 4; ni++)
            bfr[ni] = *reinterpret_cast<const short8*>(
                &Blds[(wn + ni * 16 + (lane & 15)) * 32 + (lane >> 4) * 8]);
#pragma unroll
        for (int mi = 0; mi < 4; mi++)
#pragma unroll
            for (int ni = 0; ni < 4; ni++)
                acc[mi][ni] = MFMA_BF16(af[mi], bfr[ni], acc[mi][ni]);
    }

    // epilogue: D layout row=(lane>>4)*4+r, col=lane&15
    if (OUT_BF16) {
        unsigned short* C = (unsigned short*)Cout;
#pragma unroll
        for (int mi = 0; mi < 4; mi++)
#pragma unroll
            for (int rr = 0; rr < 4; rr++) {
                int row = m0 + wm + mi * 16 + (lane >> 4) * 4 + rr;
                if (row < M) {
                    long rbase = (long)row * N + n0 + wn + (lane & 15);
#pragma unroll
                    for (int ni = 0; ni < 4; ni++)
                        C[rbase + ni * 16] = f2bf(acc[mi][ni][rr]);
                }
            }
    } else {
        float* C = (float*)Cout;
        float bv[4];
#pragma unroll
        for (int ni = 0; ni < 4; ni++) bv[ni] = bias[n0 + wn + ni * 16 + (lane & 15)];
#pragma unroll
        for (int mi = 0; mi < 4; mi++)
#pragma unroll
            for (int rr = 0; rr < 4; rr++) {
                int row = m0 + wm + mi * 16 + (lane >> 4) * 4 + rr;
                if (row < M) {
                    long rbase = (long)row * N + n0 + wn + (lane & 15);
#pragma unroll
                    for (int ni = 0; ni < 4; ni++)
                        C[rbase + ni * 16] = acc[mi][ni][rr] + bv[ni];
                }
            }
    }
}

// ---------------- fused attention: one block per (b,h) ----------------
// qkv: [B*197][2304] bf16 rows (q|k|v each [12 heads][64]); out: [B*197][768] bf16
__global__ __launch_bounds__(448, 2) void attn_kernel(
    const unsigned short* __restrict__ qkv,
    const float* __restrict__ scale,
    unsigned short* __restrict__ out) {
    const int N = 197, D3 = 2304;
    int b = blockIdx.x / 12, h = blockIdx.x % 12;
    int tid = threadIdx.x, lane = tid & 63, wave = tid >> 6;

    __shared__ __align__(16) unsigned short Klds[224 * 64];   // [key row][d], 16B slots XOR (r&7)
    __shared__ __align__(16) unsigned short Vlds[64 * 224];   // [d][j], 16B slots XOR (d&3)
    __shared__ __align__(16) unsigned short Plds[7 * 16 * 32];// per-wave P chunk, slots XOR (row&3)

    const unsigned short* base = qkv + (long)b * N * D3 + h * 64;

    // stage K (zero-pad rows >= N), swizzled
    for (int idx = tid; idx < 224 * 8; idx += 448) {
        int r = idx >> 3, s = idx & 7;
        short8 v = {0, 0, 0, 0, 0, 0, 0, 0};
        if (r < N) v = *reinterpret_cast<const short8*>(base + (long)r * D3 + 768 + s * 8);
        *reinterpret_cast<short8*>(&Klds[r * 64 + (s ^ (r & 7)) * 8]) = v;
    }
    // stage V transposed (Vlds[d][j]), zero-pad
    for (int idx = tid; idx < 224 * 8; idx += 448) {
        int j = idx >> 3, sg = idx & 7;
        short8 v = {0, 0, 0, 0, 0, 0, 0, 0};
        if (j < N) v = *reinterpret_cast<const short8*>(base + (long)j * D3 + 1536 + sg * 8);
        int s = j >> 3;
#pragma unroll
        for (int e = 0; e < 8; e++) {
            int d = sg * 8 + e;
            Vlds[d * 224 + (s ^ (d & 3)) * 8 + (j & 7)] = (unsigned short)v[e];
        }
    }
    __syncthreads();

    float sc = scale[h];
    unsigned short* Pw = &Plds[wave * (16 * 32)];

    for (int rtb = 0; rtb < 2; rtb++) {
        int rt = wave + rtb * 7;  // 0..13
        int i0 = rt * 16;
        // Q fragments (A operand: row = lane&15, k = (lane>>4)*8+e), clamped global rows
        int qrow = i0 + (lane & 15); if (qrow > N - 1) qrow = N - 1;
        const unsigned short* qp = base + (long)qrow * D3;
        short8 qf[2];
#pragma unroll
        for (int kb = 0; kb < 2; kb++)
            qf[kb] = *reinterpret_cast<const short8*>(qp + kb * 32 + (lane >> 4) * 8);

        // S = Q @ K^T  (B operand row j = lane&15 reads K row contiguously)
        floatx4 sf[14];
#pragma unroll
        for (int jt = 0; jt < 14; jt++) sf[jt] = (floatx4){0.f, 0.f, 0.f, 0.f};
#pragma unroll
        for (int jt = 0; jt < 14; jt++) {
#pragma unroll
            for (int kb = 0; kb < 2; kb++) {
                int r = jt * 16 + (lane & 15);
                int slot = kb * 4 + (lane >> 4);
                short8 kf = *reinterpret_cast<const short8*>(
                    &Klds[r * 64 + (slot ^ (r & 7)) * 8]);
                sf[jt] = MFMA_BF16(qf[kb], kf, sf[jt]);
            }
        }

        // softmax over j (rows: (lane>>4)*4+rr; cols: jt*16 + (lane&15))
        int rowg[4];
        float mx[4], sm[4];
#pragma unroll
        for (int rr = 0; rr < 4; rr++) { rowg[rr] = i0 + (lane >> 4) * 4 + rr; mx[rr] = -1e30f; }
#pragma unroll
        for (int jt = 0; jt < 14; jt++) {
            int col = jt * 16 + (lane & 15);
#pragma unroll
            for (int rr = 0; rr < 4; rr++) {
                float v = sf[jt][rr] * sc;
                if (col >= N || col == rowg[rr]) v = -1e30f;  // tail + diagonal mask
                sf[jt][rr] = v;
                mx[rr] = fmaxf(mx[rr], v);
            }
        }
#pragma unroll
        for (int rr = 0; rr < 4; rr++) {
#pragma unroll
            for (int m = 1; m <= 8; m <<= 1)
                mx[rr] = fmaxf(mx[rr], __shfl_xor(mx[rr], m, 64));
            sm[rr] = 0.f;
        }
#pragma unroll
        for (int jt = 0; jt < 14; jt++)
#pragma unroll
            for (int rr = 0; rr < 4; rr++) {
                float p = __expf(sf[jt][rr] - mx[rr]);
                sf[jt][rr] = p;
                sm[rr] += p;
            }
#pragma unroll
        for (int rr = 0; rr < 4; rr++)
#pragma unroll
            for (int m = 1; m <= 8; m <<= 1)
                sm[rr] += __shfl_xor(sm[rr], m, 64);

        // PV: per 32-col chunk, transpose P via per-wave LDS, then 4 MFMAs vs V^T
        floatx4 oacc[4];
#pragma unroll
        for (int dt = 0; dt < 4; dt++) oacc[dt] = (floatx4){0.f, 0.f, 0.f, 0.f};
#pragma unroll
        for (int c = 0; c < 7; c++) {
#pragma unroll
            for (int jh = 0; jh < 2; jh++) {
#pragma unroll
                for (int rr = 0; rr < 4; rr++) {
                    int row = (lane >> 4) * 4 + rr;
                    int jj = jh * 16 + (lane & 15);
                    Pw[row * 32 + ((jj >> 3) ^ (row & 3)) * 8 + (jj & 7)] =
                        f2bf(sf[c * 2 + jh][rr]);
                }
            }
            int prow = lane & 15;
            short8 pa = *reinterpret_cast<const short8*>(
                &Pw[prow * 32 + (((lane >> 4)) ^ (prow & 3)) * 8]);
#pragma unroll
            for (int dt = 0; dt < 4; dt++) {
                int d = dt * 16 + (lane & 15);
                int slot = c * 4 + (lane >> 4);
                short8 vf = *reinterpret_cast<const short8*>(
                    &Vlds[d * 224 + (slot ^ (d & 3)) * 8]);
                oacc[dt] = MFMA_BF16(pa, vf, oacc[dt]);
            }
        }

        // write out (divide by softmax denom here)
#pragma unroll
        for (int rr = 0; rr < 4; rr++) {
            int n = rowg[rr];
            if (n < N) {
                float r = 1.f / sm[rr];
                long o = ((long)b * N + n) * 768 + h * 64;
#pragma unroll
                for (int dt = 0; dt < 4; dt++)
                    out[o + dt * 16 + (lane & 15)] = f2bf(oacc[dt][rr] * r);
            }
        }
    }
}

extern "C" void kernel_launch(void* const* d_in, const int* in_sizes, int n_in,
                              void* d_out, int out_size, void* d_ws, size_t ws_size,
                              hipStream_t stream) {
    (void)in_sizes; (void)n_in; (void)out_size; (void)ws_size;
    const float* x     = (const float*)d_in[0];
    const float* scale = (const float*)d_in[1];
    const float* Wqkv  = (const float*)d_in[2];
    const float* Wout  = (const float*)d_in[3];
    const float* bout  = (const float*)d_in[4];
    float* out = (float*)d_out;

    const int M = 12608;  // 64*197
    char* ws = (char*)d_ws;
    unsigned short* x_bf   = (unsigned short*)(ws);                     // 19365888 B
    unsigned short* wqkv_t = (unsigned short*)(ws + 19365888);          //  3538944 B
    unsigned short* wout_t = (unsigned short*)(ws + 22904832);          //  1179648 B
    unsigned short* qkv    = (unsigned short*)(ws + 24084480);          // 58097664 B
    unsigned short* ao     = (unsigned short*)(ws + 82182144);          // 19365888 B

    cast_f32_to_bf16<<<2048, 256, 0, stream>>>(x, x_bf, (M * 768) / 4);
    transpose_cast<<<dim3(2304 / 32, 768 / 32), dim3(32, 8), 0, stream>>>(Wqkv, wqkv_t, 768, 2304);
    transpose_cast<<<dim3(768 / 32, 768 / 32), dim3(32, 8), 0, stream>>>(Wout, wout_t, 768, 768);
    gemm_bt<true><<<dim3(2304 / 128, 99), 256, 0, stream>>>(x_bf, wqkv_t, qkv, nullptr, M, 2304, 768);
    attn_kernel<<<768, 448, 0, stream>>>(qkv, scale, ao);
    gemm_bt<false><<<dim3(768 / 128, 99), 256, 0, stream>>>(ao, wout_t, out, bout, M, 768, 768);
}

// Round 3
// 204.652 us; speedup vs baseline: 1.1376x; 1.0738x over previous
//
#include <hip/hip_runtime.h>
#include <hip/hip_bf16.h>

typedef __attribute__((ext_vector_type(8))) short short8;
typedef __attribute__((ext_vector_type(4))) float floatx4;

#define MFMA_BF16(a, b, c) __builtin_amdgcn_mfma_f32_16x16x32_bf16((a), (b), (c), 0, 0, 0)

__device__ __forceinline__ unsigned short f2bf(float f) {
    union { float f; unsigned u; } v; v.f = f;
    unsigned r = v.u + 0x7fffu + ((v.u >> 16) & 1u);
    return (unsigned short)(r >> 16);
}

// async global->LDS, 16B per lane (global_load_lds_dwordx4)
__device__ __forceinline__ void gload16(const unsigned short* g, unsigned short* l) {
    __builtin_amdgcn_global_load_lds(
        (const __attribute__((address_space(1))) unsigned int*)g,
        (__attribute__((address_space(3))) unsigned int*)l, 16, 0, 0);
}

// ---------------- elementwise cast f32 -> bf16 ----------------
__global__ void cast_f32_to_bf16(const float* __restrict__ src,
                                 unsigned short* __restrict__ dst, int n4) {
    int i = blockIdx.x * blockDim.x + threadIdx.x;
    int stride = gridDim.x * blockDim.x;
    for (; i < n4; i += stride) {
        float4 f = reinterpret_cast<const float4*>(src)[i];
        ushort4 o;
        o.x = f2bf(f.x); o.y = f2bf(f.y); o.z = f2bf(f.z); o.w = f2bf(f.w);
        reinterpret_cast<ushort4*>(dst)[i] = o;
    }
}

// ---------- transpose + cast: src[R][C] f32 -> dst[C][R] bf16 (R,C multiples of 32) ----------
__global__ void transpose_cast(const float* __restrict__ src,
                               unsigned short* __restrict__ dst, int R, int C) {
    __shared__ float tile[32][33];
    int c0 = blockIdx.x * 32, r0 = blockIdx.y * 32;
    int tx = threadIdx.x, ty = threadIdx.y;
#pragma unroll
    for (int i = 0; i < 32; i += 8)
        tile[ty + i][tx] = src[(long)(r0 + ty + i) * C + (c0 + tx)];
    __syncthreads();
#pragma unroll
    for (int i = 0; i < 32; i += 8)
        dst[(long)(c0 + ty + i) * R + (r0 + tx)] = f2bf(tile[tx][ty + i]);
}

// ---------------- 128x128 bf16 MFMA GEMM, BK=64, swizzled LDS, B given as B^T ----------------
// C[m][n] = sum_k A[m][k] * B[n][k].
// LDS [128][64] shorts per operand; 16B-slot XOR-swizzle (slot ^ (row&7)):
// linear global_load_lds dest + inverse-swizzled global SOURCE + swizzled ds_read (rule #21).
template <bool OUT_BF16>
__global__ __launch_bounds__(256, 4) void gemm_bt(
    const unsigned short* __restrict__ A,   // [M][K] bf16
    const unsigned short* __restrict__ B,   // [N][K] bf16
    void* __restrict__ Cout,
    const float* __restrict__ bias,
    int M, int N, int K) {
    __shared__ __align__(16) unsigned short Alds[128 * 64];
    __shared__ __align__(16) unsigned short Blds[128 * 64];

    int tid = threadIdx.x;
    int lane = tid & 63, wave = tid >> 6;
    int m0 = blockIdx.y * 128, n0 = blockIdx.x * 128;
    int wm = (wave >> 1) * 64, wn = (wave & 1) * 64;

    floatx4 acc[4][4];
#pragma unroll
    for (int mi = 0; mi < 4; mi++)
#pragma unroll
        for (int ni = 0; ni < 4; ni++) acc[mi][ni] = (floatx4){0.f, 0.f, 0.f, 0.f};

    // staging: thread t, chunk i covers LDS row (i*32 + t>>3), 16B slot (t&7) [linear dest]
    // source k-offset is the swizzle-inverse: slot' = (t&7) ^ (row&7); row&7 == (t>>3)&7
    int srow = tid >> 3;                               // 0..31
    int scol = (((tid & 7) ^ (srow & 7)) << 3);        // swizzled source offset (shorts)
    const unsigned short* ap[4];
    const unsigned short* bp[4];
    unsigned short* la[4];
    unsigned short* lb[4];
#pragma unroll
    for (int i = 0; i < 4; i++) {
        int row = i * 32 + srow;
        int ar = m0 + row; if (ar >= M) ar = M - 1;
        ap[i] = A + (long)ar * K + scol;
        bp[i] = B + (long)(n0 + row) * K + scol;
        la[i] = &Alds[row * 64 + (tid & 7) * 8];
        lb[i] = &Blds[row * 64 + (tid & 7) * 8];
    }

    for (int k0 = 0; k0 < K; k0 += 64) {
        __syncthreads();              // previous iter's reads done before overwrite
#pragma unroll
        for (int i = 0; i < 4; i++) gload16(ap[i] + k0, la[i]);
#pragma unroll
        for (int i = 0; i < 4; i++) gload16(bp[i] + k0, lb[i]);
        __syncthreads();              // drains vmcnt(0) + joins

#pragma unroll
        for (int ks = 0; ks < 2; ks++) {
            int sw = ((ks * 4 + (lane >> 4)) ^ (lane & 7)) * 8;  // swizzled read slot
            short8 af[4], bfr[4];
#pragma unroll
            for (int mi = 0; mi < 4; mi++)
                af[mi] = *reinterpret_cast<const short8*>(
                    &Alds[(wm + mi * 16 + (lane & 15)) * 64 + sw]);
#pragma unroll
            for (int ni = 0; ni < 4; ni++)
                bfr[ni] = *reinterpret_cast<const short8*>(
                    &Blds[(wn + ni * 16 + (lane & 15)) * 64 + sw]);
#pragma unroll
            for (int mi = 0; mi < 4; mi++)
#pragma unroll
                for (int ni = 0; ni < 4; ni++)
                    acc[mi][ni] = MFMA_BF16(af[mi], bfr[ni], acc[mi][ni]);
        }
    }

    // epilogue: D layout row=(lane>>4)*4+r, col=lane&15
    if (OUT_BF16) {
        unsigned short* C = (unsigned short*)Cout;
#pragma unroll
        for (int mi = 0; mi < 4; mi++)
#pragma unroll
            for (int rr = 0; rr < 4; rr++) {
                int row = m0 + wm + mi * 16 + (lane >> 4) * 4 + rr;
                if (row < M) {
                    long rbase = (long)row * N + n0 + wn + (lane & 15);
#pragma unroll
                    for (int ni = 0; ni < 4; ni++)
                        C[rbase + ni * 16] = f2bf(acc[mi][ni][rr]);
                }
            }
    } else {
        float* C = (float*)Cout;
        float bv[4];
#pragma unroll
        for (int ni = 0; ni < 4; ni++) bv[ni] = bias[n0 + wn + ni * 16 + (lane & 15)];
#pragma unroll
        for (int mi = 0; mi < 4; mi++)
#pragma unroll
            for (int rr = 0; rr < 4; rr++) {
                int row = m0 + wm + mi * 16 + (lane >> 4) * 4 + rr;
                if (row < M) {
                    long rbase = (long)row * N + n0 + wn + (lane & 15);
#pragma unroll
                    for (int ni = 0; ni < 4; ni++)
                        C[rbase + ni * 16] = acc[mi][ni][rr] + bv[ni];
                }
            }
    }
}

// ---------------- fused attention: one block per (b,h) ----------------
// qkv: [B*197][2304] bf16 rows (q|k|v each [12 heads][64]); out: [B*197][768] bf16
// 13 column-tiles (208 >= 197) instead of 14.
__global__ __launch_bounds__(448, 2) void attn_kernel(
    const unsigned short* __restrict__ qkv,
    const float* __restrict__ scale,
    unsigned short* __restrict__ out) {
    const int N = 197, D3 = 2304;
    const int NT = 13;                 // 13*16 = 208 >= 197
    int b = blockIdx.x / 12, h = blockIdx.x % 12;
    int tid = threadIdx.x, lane = tid & 63, wave = tid >> 6;

    __shared__ __align__(16) unsigned short Klds[208 * 64];   // [key row][d], 16B slots XOR (r&7)
    __shared__ __align__(16) unsigned short Vlds[64 * 224];   // [d][j], 16B slots XOR (d&3)
    __shared__ __align__(16) unsigned short Plds[7 * 16 * 32];// per-wave P chunk, slots XOR (row&3)

    const unsigned short* base = qkv + (long)b * N * D3 + h * 64;

    // stage K (zero-pad rows >= N), swizzled
    for (int idx = tid; idx < 208 * 8; idx += 448) {
        int r = idx >> 3, s = idx & 7;
        short8 v = {0, 0, 0, 0, 0, 0, 0, 0};
        if (r < N) v = *reinterpret_cast<const short8*>(base + (long)r * D3 + 768 + s * 8);
        *reinterpret_cast<short8*>(&Klds[r * 64 + (s ^ (r & 7)) * 8]) = v;
    }
    // stage V transposed (Vlds[d][j]), zero-pad
    for (int idx = tid; idx < 224 * 8; idx += 448) {
        int j = idx >> 3, sg = idx & 7;
        short8 v = {0, 0, 0, 0, 0, 0, 0, 0};
        if (j < N) v = *reinterpret_cast<const short8*>(base + (long)j * D3 + 1536 + sg * 8);
        int s = j >> 3;
#pragma unroll
        for (int e = 0; e < 8; e++) {
            int d = sg * 8 + e;
            Vlds[d * 224 + (s ^ (d & 3)) * 8 + (j & 7)] = (unsigned short)v[e];
        }
    }
    __syncthreads();

    float sc = scale[h];
    unsigned short* Pw = &Plds[wave * (16 * 32)];

    for (int rtb = 0; rtb < 2; rtb++) {
        int rt = wave + rtb * 7;  // 0..13
        int i0 = rt * 16;
        // Q fragments (A operand: row = lane&15, k = (lane>>4)*8+e), clamped global rows
        int qrow = i0 + (lane & 15); if (qrow > N - 1) qrow = N - 1;
        const unsigned short* qp = base + (long)qrow * D3;
        short8 qf[2];
#pragma unroll
        for (int kb = 0; kb < 2; kb++)
            qf[kb] = *reinterpret_cast<const short8*>(qp + kb * 32 + (lane >> 4) * 8);

        // S = Q @ K^T  (B operand row j = lane&15 reads K row contiguously)
        floatx4 sf[NT];
#pragma unroll
        for (int jt = 0; jt < NT; jt++) sf[jt] = (floatx4){0.f, 0.f, 0.f, 0.f};
#pragma unroll
        for (int jt = 0; jt < NT; jt++) {
#pragma unroll
            for (int kb = 0; kb < 2; kb++) {
                int r = jt * 16 + (lane & 15);
                int slot = kb * 4 + (lane >> 4);
                short8 kf = *reinterpret_cast<const short8*>(
                    &Klds[r * 64 + (slot ^ (r & 7)) * 8]);
                sf[jt] = MFMA_BF16(qf[kb], kf, sf[jt]);
            }
        }

        // softmax over j (rows: (lane>>4)*4+rr; cols: jt*16 + (lane&15))
        int rowg[4];
        float mx[4], sm[4];
#pragma unroll
        for (int rr = 0; rr < 4; rr++) { rowg[rr] = i0 + (lane >> 4) * 4 + rr; mx[rr] = -1e30f; }
#pragma unroll
        for (int jt = 0; jt < NT; jt++) {
            int col = jt * 16 + (lane & 15);
#pragma unroll
            for (int rr = 0; rr < 4; rr++) {
                float v = sf[jt][rr] * sc;
                if (col >= N || col == rowg[rr]) v = -1e30f;  // tail + diagonal mask
                sf[jt][rr] = v;
                mx[rr] = fmaxf(mx[rr], v);
            }
        }
#pragma unroll
        for (int rr = 0; rr < 4; rr++) {
#pragma unroll
            for (int m = 1; m <= 8; m <<= 1)
                mx[rr] = fmaxf(mx[rr], __shfl_xor(mx[rr], m, 64));
            sm[rr] = 0.f;
        }
#pragma unroll
        for (int jt = 0; jt < NT; jt++)
#pragma unroll
            for (int rr = 0; rr < 4; rr++) {
                float p = __expf(sf[jt][rr] - mx[rr]);
                sf[jt][rr] = p;
                sm[rr] += p;
            }
#pragma unroll
        for (int rr = 0; rr < 4; rr++)
#pragma unroll
            for (int m = 1; m <= 8; m <<= 1)
                sm[rr] += __shfl_xor(sm[rr], m, 64);

        // PV: per 32-col chunk, transpose P via per-wave LDS, then 4 MFMAs vs V^T
        floatx4 oacc[4];
#pragma unroll
        for (int dt = 0; dt < 4; dt++) oacc[dt] = (floatx4){0.f, 0.f, 0.f, 0.f};
#pragma unroll
        for (int c = 0; c < 7; c++) {
#pragma unroll
            for (int jh = 0; jh < 2; jh++) {
                int jtc = c * 2 + jh;
#pragma unroll
                for (int rr = 0; rr < 4; rr++) {
                    int row = (lane >> 4) * 4 + rr;
                    int jj = jh * 16 + (lane & 15);
                    float pv = (jtc < NT) ? sf[jtc < NT ? jtc : 0][rr] : 0.f;
                    Pw[row * 32 + ((jj >> 3) ^ (row & 3)) * 8 + (jj & 7)] = f2bf(pv);
                }
            }
            int prow = lane & 15;
            short8 pa = *reinterpret_cast<const short8*>(
                &Pw[prow * 32 + (((lane >> 4)) ^ (prow & 3)) * 8]);
#pragma unroll
            for (int dt = 0; dt < 4; dt++) {
                int d = dt * 16 + (lane & 15);
                int slot = c * 4 + (lane >> 4);
                short8 vf = *reinterpret_cast<const short8*>(
                    &Vlds[d * 224 + (slot ^ (d & 3)) * 8]);
                oacc[dt] = MFMA_BF16(pa, vf, oacc[dt]);
            }
        }

        // write out (divide by softmax denom here)
#pragma unroll
        for (int rr = 0; rr < 4; rr++) {
            int n = rowg[rr];
            if (n < N) {
                float r = 1.f / sm[rr];
                long o = ((long)b * N + n) * 768 + h * 64;
#pragma unroll
                for (int dt = 0; dt < 4; dt++)
                    out[o + dt * 16 + (lane & 15)] = f2bf(oacc[dt][rr] * r);
            }
        }
    }
}

extern "C" void kernel_launch(void* const* d_in, const int* in_sizes, int n_in,
                              void* d_out, int out_size, void* d_ws, size_t ws_size,
                              hipStream_t stream) {
    (void)in_sizes; (void)n_in; (void)out_size; (void)ws_size;
    const float* x     = (const float*)d_in[0];
    const float* scale = (const float*)d_in[1];
    const float* Wqkv  = (const float*)d_in[2];
    const float* Wout  = (const float*)d_in[3];
    const float* bout  = (const float*)d_in[4];
    float* out = (float*)d_out;

    const int M = 12608;  // 64*197
    char* ws = (char*)d_ws;
    unsigned short* x_bf   = (unsigned short*)(ws);                     // 19365888 B
    unsigned short* wqkv_t = (unsigned short*)(ws + 19365888);          //  3538944 B
    unsigned short* wout_t = (unsigned short*)(ws + 22904832);          //  1179648 B
    unsigned short* qkv    = (unsigned short*)(ws + 24084480);          // 58097664 B
    unsigned short* ao     = (unsigned short*)(ws + 82182144);          // 19365888 B

    cast_f32_to_bf16<<<2048, 256, 0, stream>>>(x, x_bf, (M * 768) / 4);
    transpose_cast<<<dim3(2304 / 32, 768 / 32), dim3(32, 8), 0, stream>>>(Wqkv, wqkv_t, 768, 2304);
    transpose_cast<<<dim3(768 / 32, 768 / 32), dim3(32, 8), 0, stream>>>(Wout, wout_t, 768, 768);
    gemm_bt<true><<<dim3(2304 / 128, 99), 256, 0, stream>>>(x_bf, wqkv_t, qkv, nullptr, M, 2304, 768);
    attn_kernel<<<768, 448, 0, stream>>>(qkv, scale, ao);
    gemm_bt<false><<<dim3(768 / 128, 99), 256, 0, stream>>>(ao, wout_t, out, bout, M, 768, 768);
}